// Round 19
// baseline (228.326 us; speedup 1.0000x reference)
//
#include <hip/hip_runtime.h>
#include <hip/hip_bf16.h>

typedef __attribute__((ext_vector_type(8))) short bf16x8;
typedef __attribute__((ext_vector_type(4))) float f32x4;

#define NBUCK 391    // ceil(100000/256) buckets of 256 nodes (dst>>8)
#define BCAP 8192    // slots per bucket; avg fill ~4096 -> never overflows

// ---------------- helpers ----------------

__device__ __forceinline__ ushort f2bf(float f) {
    unsigned int b = __float_as_uint(f);
    unsigned int r = (b + 0x7fffu + ((b >> 16) & 1u)) >> 16;  // RNE
    return (ushort)r;
}
// HW packed convert (RNE), no builtin on gfx950 -> inline asm [T12 recipe]
__device__ __forceinline__ uint cvt_pk_bf16(float lo, float hi) {
    uint r;
    asm("v_cvt_pk_bf16_f32 %0, %1, %2" : "=v"(r) : "v"(lo), "v"(hi));
    return r;
}
__device__ __forceinline__ float bflo(uint v) { return __uint_as_float(v << 16); }
__device__ __forceinline__ float bfhi(uint v) { return __uint_as_float(v & 0xffff0000u); }

// ---------------- phase B1: bucket edges by dst>>8 (+ weight casts + zero rows) ----------------
// blocks [0,512): per-block LDS histogram -> reservation atomic -> LDS-ranked scatter
//   (pairs packed: (dst&255)<<24 | src, src<2^17)
// blocks [512,640): W1t cast; [640,768): W2t cast; block 768: zero rows of tbl1/tbl2

__global__ __launch_bounds__(256) void bucket_kernel(const int* __restrict__ src, const int* __restrict__ dst,
                                                     int* __restrict__ gcur, uint* __restrict__ pairs,
                                                     int E, int chunk,
                                                     const float* __restrict__ W1, ushort* __restrict__ W1t,
                                                     const float* __restrict__ W2, ushort* __restrict__ W2t,
                                                     uint* __restrict__ tbl1z, uint* __restrict__ tbl2z) {
    int b = blockIdx.x, t = threadIdx.x;
    if (b >= 512) {
        if (b < 640) {
            int i = (b - 512) * 256 + t;       // W1t[n][k], n in [0,256), k in [0,128)
            int n = i >> 7, k = i & 127;
            W1t[i] = f2bf(W1[(size_t)k * 256 + n]);
        } else if (b < 768) {
            int i = (b - 640) * 256 + t;       // W2t[n][k], n in [0,128), k in [0,256)
            int n = i >> 8, k = i & 255;
            W2t[i] = f2bf(W2[(size_t)k * 128 + n]);
        } else {
            if (t < 64) { tbl1z[t] = 0u; tbl2z[t] = 0u; }
        }
        return;
    }
    __shared__ int lcnt[NBUCK];
    for (int q = t; q < NBUCK; q += 256) lcnt[q] = 0;
    __syncthreads();
    int e0 = b * chunk;
    int e1 = e0 + chunk; if (e1 > E) e1 = E;
    for (int e = e0 + t; e < e1; e += 256)
        atomicAdd(&lcnt[dst[e] >> 8], 1);
    __syncthreads();
    for (int q = t; q < NBUCK; q += 256) {
        int c = lcnt[q];
        lcnt[q] = c ? atomicAdd(&gcur[q], c) : 0;   // lcnt becomes running in-bucket cursor
    }
    __syncthreads();
    for (int e = e0 + t; e < e1; e += 256) {
        int d = dst[e];
        uint s = (uint)src[e];
        int bb = d >> 8;
        int p = atomicAdd(&lcnt[bb], 1);
        if (p < BCAP) pairs[(size_t)bb * BCAP + p] = ((uint)(d & 255) << 24) | s;
    }
}

// ---------------- phase B2: per-bucket tight CSR + deg -> dis + pre-scaled tbl1 rows ----------------
// bbase computed in-block (reduction over gcur[q<b]).

__global__ __launch_bounds__(256) void csr_kernel(const uint* __restrict__ pairs, const int* __restrict__ gcur,
                                                  int* __restrict__ offs, float* __restrict__ dis,
                                                  int* __restrict__ csr,
                                                  const float4* __restrict__ emb4, ushort4* __restrict__ tbl4,
                                                  int Nn, int E) {
    int b = blockIdx.x;
    int n0 = b << 8;
    int ne = min(gcur[b], BCAP);
    __shared__ int cnt[256], off[256], pos[256];
    __shared__ float sdis[256];
    __shared__ int wred[4];
    int i = threadIdx.x;
    int lane = i & 63, wid = i >> 6;

    // in-block bbase = sum_{q<b} min(gcur[q],BCAP)
    int partial = 0;
    for (int q = i; q < b; q += 256) partial += min(gcur[q], BCAP);
#pragma unroll
    for (int d = 1; d < 64; d <<= 1) partial += __shfl_xor(partial, d, 64);
    if (lane == 0) wred[wid] = partial;
    cnt[i] = 0;
    __syncthreads();
    int base = wred[0] + wred[1] + wred[2] + wred[3];

    const uint* pp = pairs + (size_t)b * BCAP;
    for (int e = i; e < ne; e += 256)
        atomicAdd(&cnt[pp[e] >> 24], 1);
    __syncthreads();
    int v = cnt[i];
    int x = v;
#pragma unroll
    for (int d = 1; d < 64; d <<= 1) {
        int y = __shfl_up(x, d, 64);
        if (lane >= d) x += y;
    }
    __shared__ int wsum[4], wpre[4];
    if (lane == 63) wsum[wid] = x;
    __syncthreads();
    if (i == 0) {
        int run = 0;
        for (int w = 0; w < 4; ++w) { wpre[w] = run; run += wsum[w]; }
    }
    __syncthreads();
    int excl = x - v + wpre[wid];
    off[i] = excl;
    pos[i] = 0;
    int n = n0 + i;
    float s = rsqrtf((float)v + 1.0f);
    sdis[i] = s;
    if (n < Nn) {
        offs[n] = base + excl;
        dis[n] = s;
    }
    if (b == 0 && i == 0) offs[Nn] = E;
    __syncthreads();
    for (int e = i; e < ne; e += 256) {
        uint r = pp[e];
        int li = (int)(r >> 24);
        int p = atomicAdd(&pos[li], 1);
        csr[base + off[li] + p] = (int)(r & 0xFFFFFFu);
    }
    // fused cast: tbl1 rows for this bucket's 256 nodes (dis pre-scaled bf16, cvt_pk)
    for (int q = i; q < 256 * 32; q += 256) {
        int rw = q >> 5;
        int nn = n0 + rw;
        if (nn < Nn) {
            float sc = sdis[rw];
            float4 vv = emb4[(size_t)nn * 32 + (q & 31)];
            uint2 o;
            o.x = cvt_pk_bf16(vv.x * sc, vv.y * sc);
            o.y = cvt_pk_bf16(vv.z * sc, vv.w * sc);
            reinterpret_cast<uint2*>(tbl4)[(size_t)nn * 32 + (q & 31)] = o;
        }
    }
}

// ---------------- aggregation: 2 nodes/wave, dwordx2 gathers, batch 16, zero-row tails ----------------
// half-wave h owns node 2*wave+h; lane i31 owns cols 4*i31..4*i31+3 (uint2 = 8B).
// All 16 gathers issued before any accumulation -> 16 outstanding 256B loads per
// half-wave (latency-bound fix; r18 evidence: VALU 30%, dur flat -> latency-bound).
// Tail slots gather table row Nn (all zeros, L1-hot) -> no per-element cndmask.

template <bool BIAS, bool BF16OUT>
__global__ __launch_bounds__(256) void agg2x(const uint2* __restrict__ tbl2x,  // [Nn+1][32], row Nn = 0
                                             const int* __restrict__ offs,
                                             const int* __restrict__ rec,
                                             const float* __restrict__ dis,
                                             const float* __restrict__ bias,
                                             void* __restrict__ outp, int Nn) {
    int wave = (int)((blockIdx.x * 256 + threadIdx.x) >> 6);
    int lane = threadIdx.x & 63;
    int i31 = lane & 31;
    int gw = wave * 2 + (lane >> 5);
    bool valid = gw < Nn;
    int gc = valid ? gw : Nn - 1;
    float dn = dis[gc];
    int e0 = offs[gc], e1 = offs[gc + 1];
    uint ZR = (uint)Nn;
    uint2 hv = tbl2x[(size_t)gc * 32 + i31];
    float a0 = bflo(hv.x), a1 = bfhi(hv.x), a2 = bflo(hv.y), a3 = bfhi(hv.y);

    for (int base = e0; __any(base < e1); base += 16) {
        int ee = base + (i31 & 15);
        uint myidx = (ee < e1) ? (uint)rec[ee] : ZR;   // one select per 16 edges
        uint2 vv[16];
#pragma unroll
        for (int j = 0; j < 16; ++j) {
            uint idx = (uint)__shfl((int)myidx, j, 32);
            vv[j] = tbl2x[(size_t)idx * 32u + (uint)i31];
        }
#pragma unroll
        for (int j = 0; j < 16; ++j) {
            a0 += bflo(vv[j].x); a1 += bfhi(vv[j].x);
            a2 += bflo(vv[j].y); a3 += bfhi(vv[j].y);
        }
    }

    a0 *= dn; a1 *= dn; a2 *= dn; a3 *= dn;
    if (BIAS) {
        float4 bv = reinterpret_cast<const float4*>(bias)[i31];
        a0 += bv.x; a1 += bv.y; a2 += bv.z; a3 += bv.w;
    }
    if (valid) {
        if (BF16OUT) {
            uint2 o;
            o.x = cvt_pk_bf16(a0, a1);
            o.y = cvt_pk_bf16(a2, a3);
            reinterpret_cast<uint2*>(outp)[(size_t)gw * 32 + i31] = o;
        } else {
            float4 o = make_float4(a0, a1, a2, a3);
            reinterpret_cast<float4*>(outp)[(size_t)gw * 32 + i31] = o;
        }
    }
}

// ---------------- 8-wave fused GEMM: x = L2norm(A@W1+b1); tbl2 = dis*(x@W2) ----------------
// 512 threads. A-tile [64][128] bf16 staged into the FIRST 16KB of xt (sA/xt
// union: sA is dead after stage 1; the ssl barrier guarantees all stage-1 reads
// completed before xt writes overwrite it). LDS 34KB -> 4 blocks/CU. N split 8
// ways; W2 frags loaded after the norm barrier. bf16 packing via v_cvt_pk_bf16_f32.
// mfma_f32_16x16x32_bf16: A row=lane&15,k=(lane>>4)*8+j; C/D col=lane&15,row=(lane>>4)*4+r [m89].

__global__ __launch_bounds__(512, 4) void fused_gemm(const ushort* __restrict__ A,
                                                     const ushort* __restrict__ W1t,
                                                     const float* __restrict__ bias1,
                                                     const ushort* __restrict__ W2t,
                                                     const float* __restrict__ dsc,
                                                     ushort* __restrict__ out2, int M) {
    __shared__ __align__(16) ushort xt[64 * 256];   // 32KB; first 16KB doubles as sA
    __shared__ float ssl[8][64];
    int tid = threadIdx.x;
    int lane = tid & 63, wid = tid >> 6;   // 8 waves
    int g = lane >> 4, i15 = lane & 15;
    int koff = g * 8;
    int m0 = blockIdx.x * 64;

    // ---- stage A-tile into LDS (2 x 16B per thread, coalesced, swizzled dest) ----
    {
        const char* Ab = reinterpret_cast<const char*>(A);
        char* sAb = reinterpret_cast<char*>(xt);
#pragma unroll
        for (int j = 0; j < 2; ++j) {
            int byte = j * 8192 + tid * 16;
            int row = byte >> 8;
            int grow = m0 + row; if (grow >= M) grow = M - 1;
            bf16x8 v = *reinterpret_cast<const bf16x8*>(Ab + (size_t)grow * 256 + (byte & 255));
            *reinterpret_cast<bf16x8*>(sAb + (byte ^ ((row & 7) << 4))) = v;
        }
    }

    // preload W1 frags + bias for this wave's 32 stage-1 cols
    bf16x8 b1f[2][4];
    float bv[2];
#pragma unroll
    for (int ns = 0; ns < 2; ++ns) {
        int c = wid * 32 + ns * 16 + i15;
        const bf16x8* p = reinterpret_cast<const bf16x8*>(W1t + (size_t)c * 128 + koff);
#pragma unroll
        for (int ks = 0; ks < 4; ++ks) b1f[ns][ks] = p[ks * 4];
        bv[ns] = bias1[c];
    }
    __syncthreads();

    // ---- stage 1: gemm1 K=128 -> 32 cols/wave, A from LDS ----
    const char* sAb = reinterpret_cast<const char*>(xt);
    f32x4 acc[4][2];
#pragma unroll
    for (int ms = 0; ms < 4; ++ms)
#pragma unroll
        for (int ns = 0; ns < 2; ++ns) acc[ms][ns] = (f32x4){0.f, 0.f, 0.f, 0.f};
#pragma unroll
    for (int ks = 0; ks < 4; ++ks) {
        bf16x8 a[4];
#pragma unroll
        for (int ms = 0; ms < 4; ++ms) {
            int row = ms * 16 + i15;
            int byte = row * 256 + ks * 64 + g * 16;
            a[ms] = *reinterpret_cast<const bf16x8*>(sAb + (byte ^ ((row & 7) << 4)));
        }
#pragma unroll
        for (int ms = 0; ms < 4; ++ms)
#pragma unroll
            for (int ns = 0; ns < 2; ++ns)
                acc[ms][ns] = __builtin_amdgcn_mfma_f32_16x16x32_bf16(a[ms], b1f[ns][ks], acc[ms][ns], 0, 0, 0);
    }

    // bias + row sum-of-squares partials
    float ps[4][4];
#pragma unroll
    for (int ms = 0; ms < 4; ++ms)
#pragma unroll
        for (int r = 0; r < 4; ++r) {
            float s = 0.f;
#pragma unroll
            for (int ns = 0; ns < 2; ++ns) {
                float v = acc[ms][ns][r] + bv[ns];
                acc[ms][ns][r] = v;
                s += v * v;
            }
            ps[ms][r] = s;
        }
#pragma unroll
    for (int d = 1; d < 16; d <<= 1)
#pragma unroll
        for (int ms = 0; ms < 4; ++ms)
#pragma unroll
            for (int r = 0; r < 4; ++r) ps[ms][r] += __shfl_xor(ps[ms][r], d, 64);
    if (i15 == 0) {
#pragma unroll
        for (int ms = 0; ms < 4; ++ms)
#pragma unroll
            for (int r = 0; r < 4; ++r) ssl[wid][ms * 16 + g * 4 + r] = ps[ms][r];
    }
    __syncthreads();   // all stage-1 sA reads complete -> safe to overwrite (union)

    // normalize + write x-tile to LDS (swizzled, cvt_pk pairs of ns-cols)
#pragma unroll
    for (int ms = 0; ms < 4; ++ms)
#pragma unroll
        for (int r = 0; r < 4; ++r) {
            int rt = ms * 16 + g * 4 + r;
            float tot = 0.f;
#pragma unroll
            for (int w = 0; w < 8; ++w) tot += ssl[w][rt];
            float inv = 1.0f / fmaxf(sqrtf(tot), 1e-12f);
            int sw = (rt & 7) << 3;
            int c0 = wid * 32 + i15;
            uint pk = cvt_pk_bf16(acc[ms][0][r] * inv, acc[ms][1][r] * inv);
            xt[(rt * 256 + c0) ^ sw] = (ushort)pk;
            xt[(rt * 256 + c0 + 16) ^ sw] = (ushort)(pk >> 16);
        }
    __syncthreads();

    // W2 frags for this wave's 16 stage-2 cols
    bf16x8 b2f[8];
    {
        int c = wid * 16 + i15;
        const bf16x8* p = reinterpret_cast<const bf16x8*>(W2t + (size_t)c * 256 + koff);
#pragma unroll
        for (int ks = 0; ks < 8; ++ks) b2f[ks] = p[ks * 4];
    }

    // ---- stage 2: gemm2 K=256 -> 16 cols/wave, A from LDS ----
    f32x4 acc2[4];
#pragma unroll
    for (int ms = 0; ms < 4; ++ms) acc2[ms] = (f32x4){0.f, 0.f, 0.f, 0.f};
#pragma unroll
    for (int ks = 0; ks < 8; ++ks) {
        bf16x8 a2[4];
#pragma unroll
        for (int ms = 0; ms < 4; ++ms) {
            int rowA = ms * 16 + i15;
            int eb = (rowA * 256 + koff + ks * 32) ^ ((rowA & 7) << 3);
            a2[ms] = *reinterpret_cast<const bf16x8*>(&xt[eb]);
        }
#pragma unroll
        for (int ms = 0; ms < 4; ++ms)
            acc2[ms] = __builtin_amdgcn_mfma_f32_16x16x32_bf16(a2[ms], b2f[ks], acc2[ms], 0, 0, 0);
    }

    // epilogue: scale rows by dsc, cvt_pk row-pairs, write bf16 gather table
#pragma unroll
    for (int ms = 0; ms < 4; ++ms)
#pragma unroll
        for (int rp = 0; rp < 2; ++rp) {
            int r0 = rp * 2, r1 = rp * 2 + 1;
            int row0 = m0 + ms * 16 + g * 4 + r0;
            int row1 = row0 + 1;
            float s0 = dsc[row0 < M ? row0 : M - 1];
            float s1 = dsc[row1 < M ? row1 : M - 1];
            uint pk = cvt_pk_bf16(acc2[ms][r0] * s0, acc2[ms][r1] * s1);
            if (row0 < M) out2[(size_t)row0 * 128 + wid * 16 + i15] = (ushort)pk;
            if (row1 < M) out2[(size_t)row1 * 128 + wid * 16 + i15] = (ushort)(pk >> 16);
        }
}

// ---------------- launch ----------------

extern "C" void kernel_launch(void* const* d_in, const int* in_sizes, int n_in,
                              void* d_out, int out_size, void* d_ws, size_t ws_size,
                              hipStream_t stream) {
    const float* emb = (const float*)d_in[0];
    const float* W1 = (const float*)d_in[1];
    const float* b1 = (const float*)d_in[2];
    const float* W2 = (const float*)d_in[3];
    const float* b2 = (const float*)d_in[4];
    const int* eidx = (const int*)d_in[5];

    const int Nn = in_sizes[0] / 128;   // 100000
    const int E = in_sizes[5] / 2;      // 1600000
    const int* srcp = eidx;
    const int* dstp = eidx + E;

    float* ws = (float*)d_ws;
    size_t o = 0;
    uint* tbl1 = (uint*)(ws + o);  o += (size_t)(Nn + 1) * 64;   // dis*emb bf16 [Nn+1][128], row Nn = 0
    uint* axb = (uint*)(ws + o);   o += (size_t)Nn * 64;         // agg1 out bf16 [Nn][128]
    uint* tbl2 = (uint*)(ws + o);  o += (size_t)(Nn + 1) * 64;   // dis*h2 bf16 [Nn+1][128], row Nn = 0
    ushort* W1t = (ushort*)(ws + o); o += 128 * 256 / 2;   // [256][128]
    ushort* W2t = (ushort*)(ws + o); o += 256 * 128 / 2;   // [128][256]
    float* dis = ws + o;    o += Nn;
    int* gcur = (int*)(ws + o);   o += NBUCK + 1;
    int* offs = (int*)(ws + o);   o += Nn + 16;
    int* csr = (int*)(ws + o);    o += E;
    uint* pairs = (uint*)(ws + o); o += (size_t)NBUCK * BCAP;    // 12.8MB packed

    hipMemsetAsync(gcur, 0, (NBUCK + 1) * sizeof(int), stream);

    int B1B = 512;
    int chunk = (E + B1B - 1) / B1B;           // 3125
    bucket_kernel<<<769, 256, 0, stream>>>(srcp, dstp, gcur, pairs, E, chunk, W1, W1t, W2, W2t,
                                           tbl1 + (size_t)Nn * 64, tbl2 + (size_t)Nn * 64);
    csr_kernel<<<NBUCK, 256, 0, stream>>>(pairs, gcur, offs, dis, csr,
                                          (const float4*)emb, (ushort4*)tbl1, Nn, E);

    // layer 1: aggregate pre-scaled emb (bf16 out), then 8-wave fused GEMM -> tbl2
    agg2x<false, true><<<(Nn + 7) / 8, 256, 0, stream>>>((const uint2*)tbl1, offs, csr, dis, nullptr, axb, Nn);
    fused_gemm<<<(Nn + 63) / 64, 512, 0, stream>>>((const ushort*)axb, W1t, b1, W2t, dis, (ushort*)tbl2, Nn);

    // layer 2 aggregate + bias (fp32 out)
    agg2x<true, false><<<(Nn + 7) / 8, 256, 0, stream>>>((const uint2*)tbl2, offs, csr, dis, b2, d_out, Nn);
}

// Round 20
// 226.895 us; speedup vs baseline: 1.0063x; 1.0063x over previous
//
#include <hip/hip_runtime.h>
#include <hip/hip_bf16.h>

typedef __attribute__((ext_vector_type(8))) short bf16x8;
typedef __attribute__((ext_vector_type(4))) float f32x4;

#define NBUCK 391    // ceil(100000/256) buckets of 256 nodes (dst>>8)
#define BCAP 8192    // slots per bucket; avg fill ~4096 -> never overflows

// ---------------- helpers ----------------

__device__ __forceinline__ ushort f2bf(float f) {
    unsigned int b = __float_as_uint(f);
    unsigned int r = (b + 0x7fffu + ((b >> 16) & 1u)) >> 16;  // RNE
    return (ushort)r;
}
// HW packed convert (RNE), no builtin on gfx950 -> inline asm [T12 recipe]
__device__ __forceinline__ uint cvt_pk_bf16(float lo, float hi) {
    uint r;
    asm("v_cvt_pk_bf16_f32 %0, %1, %2" : "=v"(r) : "v"(lo), "v"(hi));
    return r;
}
__device__ __forceinline__ float bflo(uint v) { return __uint_as_float(v << 16); }
__device__ __forceinline__ float bfhi(uint v) { return __uint_as_float(v & 0xffff0000u); }

// ---------------- phase B1: bucket edges by dst>>8 (+ weight casts + zero rows) ----------------
// blocks [0,512): per-block LDS histogram -> reservation atomic -> LDS-ranked scatter
//   (pairs packed: (dst&255)<<24 | src, src<2^17)
// blocks [512,640): W1t cast; [640,768): W2t cast; block 768: zero rows of tbl1/tbl2

__global__ __launch_bounds__(256) void bucket_kernel(const int* __restrict__ src, const int* __restrict__ dst,
                                                     int* __restrict__ gcur, uint* __restrict__ pairs,
                                                     int E, int chunk,
                                                     const float* __restrict__ W1, ushort* __restrict__ W1t,
                                                     const float* __restrict__ W2, ushort* __restrict__ W2t,
                                                     uint* __restrict__ tbl1z, uint* __restrict__ tbl2z) {
    int b = blockIdx.x, t = threadIdx.x;
    if (b >= 512) {
        if (b < 640) {
            int i = (b - 512) * 256 + t;       // W1t[n][k], n in [0,256), k in [0,128)
            int n = i >> 7, k = i & 127;
            W1t[i] = f2bf(W1[(size_t)k * 256 + n]);
        } else if (b < 768) {
            int i = (b - 640) * 256 + t;       // W2t[n][k], n in [0,128), k in [0,256)
            int n = i >> 8, k = i & 255;
            W2t[i] = f2bf(W2[(size_t)k * 128 + n]);
        } else {
            if (t < 64) { tbl1z[t] = 0u; tbl2z[t] = 0u; }
        }
        return;
    }
    __shared__ int lcnt[NBUCK];
    for (int q = t; q < NBUCK; q += 256) lcnt[q] = 0;
    __syncthreads();
    int e0 = b * chunk;
    int e1 = e0 + chunk; if (e1 > E) e1 = E;
    for (int e = e0 + t; e < e1; e += 256)
        atomicAdd(&lcnt[dst[e] >> 8], 1);
    __syncthreads();
    for (int q = t; q < NBUCK; q += 256) {
        int c = lcnt[q];
        lcnt[q] = c ? atomicAdd(&gcur[q], c) : 0;   // lcnt becomes running in-bucket cursor
    }
    __syncthreads();
    for (int e = e0 + t; e < e1; e += 256) {
        int d = dst[e];
        uint s = (uint)src[e];
        int bb = d >> 8;
        int p = atomicAdd(&lcnt[bb], 1);
        if (p < BCAP) pairs[(size_t)bb * BCAP + p] = ((uint)(d & 255) << 24) | s;
    }
}

// ---------------- phase B2: per-bucket tight CSR + deg -> dis + pre-scaled tbl1 rows ----------------
// bbase computed in-block (reduction over gcur[q<b]).

__global__ __launch_bounds__(256) void csr_kernel(const uint* __restrict__ pairs, const int* __restrict__ gcur,
                                                  int* __restrict__ offs, float* __restrict__ dis,
                                                  int* __restrict__ csr,
                                                  const float4* __restrict__ emb4, ushort4* __restrict__ tbl4,
                                                  int Nn, int E) {
    int b = blockIdx.x;
    int n0 = b << 8;
    int ne = min(gcur[b], BCAP);
    __shared__ int cnt[256], off[256], pos[256];
    __shared__ float sdis[256];
    __shared__ int wred[4];
    int i = threadIdx.x;
    int lane = i & 63, wid = i >> 6;

    // in-block bbase = sum_{q<b} min(gcur[q],BCAP)
    int partial = 0;
    for (int q = i; q < b; q += 256) partial += min(gcur[q], BCAP);
#pragma unroll
    for (int d = 1; d < 64; d <<= 1) partial += __shfl_xor(partial, d, 64);
    if (lane == 0) wred[wid] = partial;
    cnt[i] = 0;
    __syncthreads();
    int base = wred[0] + wred[1] + wred[2] + wred[3];

    const uint* pp = pairs + (size_t)b * BCAP;
    for (int e = i; e < ne; e += 256)
        atomicAdd(&cnt[pp[e] >> 24], 1);
    __syncthreads();
    int v = cnt[i];
    int x = v;
#pragma unroll
    for (int d = 1; d < 64; d <<= 1) {
        int y = __shfl_up(x, d, 64);
        if (lane >= d) x += y;
    }
    __shared__ int wsum[4], wpre[4];
    if (lane == 63) wsum[wid] = x;
    __syncthreads();
    if (i == 0) {
        int run = 0;
        for (int w = 0; w < 4; ++w) { wpre[w] = run; run += wsum[w]; }
    }
    __syncthreads();
    int excl = x - v + wpre[wid];
    off[i] = excl;
    pos[i] = 0;
    int n = n0 + i;
    float s = rsqrtf((float)v + 1.0f);
    sdis[i] = s;
    if (n < Nn) {
        offs[n] = base + excl;
        dis[n] = s;
    }
    if (b == 0 && i == 0) offs[Nn] = E;
    __syncthreads();
    for (int e = i; e < ne; e += 256) {
        uint r = pp[e];
        int li = (int)(r >> 24);
        int p = atomicAdd(&pos[li], 1);
        csr[base + off[li] + p] = (int)(r & 0xFFFFFFu);
    }
    // fused cast: tbl1 rows for this bucket's 256 nodes (dis pre-scaled bf16, cvt_pk)
    for (int q = i; q < 256 * 32; q += 256) {
        int rw = q >> 5;
        int nn = n0 + rw;
        if (nn < Nn) {
            float sc = sdis[rw];
            float4 vv = emb4[(size_t)nn * 32 + (q & 31)];
            uint2 o;
            o.x = cvt_pk_bf16(vv.x * sc, vv.y * sc);
            o.y = cvt_pk_bf16(vv.z * sc, vv.w * sc);
            reinterpret_cast<uint2*>(tbl4)[(size_t)nn * 32 + (q & 31)] = o;
        }
    }
}

// ---------------- aggregation: 2 nodes/wave, dwordx2 gathers, batch 8, zero-row tails ----------------
// half-wave h owns node 2*wave+h; lane i31 owns cols 4*i31..4*i31+3 (uint2 = 8B).
// Tail slots gather table row Nn (all zeros, L1-hot) -> no per-element cndmask;
// one index-select per 8 edges. out = dn*(tbl[gw] + sum_e tbl[idx[e]]) (+bias).
// [r19 A/B: batch 16 regressed (63.5 vs 61.7) -> batch 8 is the measured optimum]

template <bool BIAS, bool BF16OUT>
__global__ __launch_bounds__(256) void agg2x(const uint2* __restrict__ tbl2x,  // [Nn+1][32], row Nn = 0
                                             const int* __restrict__ offs,
                                             const int* __restrict__ rec,
                                             const float* __restrict__ dis,
                                             const float* __restrict__ bias,
                                             void* __restrict__ outp, int Nn) {
    int wave = (int)((blockIdx.x * 256 + threadIdx.x) >> 6);
    int lane = threadIdx.x & 63;
    int i31 = lane & 31;
    int gw = wave * 2 + (lane >> 5);
    bool valid = gw < Nn;
    int gc = valid ? gw : Nn - 1;
    float dn = dis[gc];
    int e0 = offs[gc], e1 = offs[gc + 1];
    uint ZR = (uint)Nn;
    uint2 hv = tbl2x[(size_t)gc * 32 + i31];
    float a0 = bflo(hv.x), a1 = bfhi(hv.x), a2 = bflo(hv.y), a3 = bfhi(hv.y);

    for (int base = e0; __any(base < e1); base += 8) {
        int ee = base + (i31 & 7);
        uint myidx = (ee < e1) ? (uint)rec[ee] : ZR;   // one select per 8 edges
        uint ix[8];
#pragma unroll
        for (int j = 0; j < 8; ++j) ix[j] = (uint)__shfl((int)myidx, j, 32);
        uint2 vv[8];
#pragma unroll
        for (int j = 0; j < 8; ++j) vv[j] = tbl2x[(size_t)ix[j] * 32u + (uint)i31];
#pragma unroll
        for (int j = 0; j < 8; ++j) {
            a0 += bflo(vv[j].x); a1 += bfhi(vv[j].x);
            a2 += bflo(vv[j].y); a3 += bfhi(vv[j].y);
        }
    }

    a0 *= dn; a1 *= dn; a2 *= dn; a3 *= dn;
    if (BIAS) {
        float4 bv = reinterpret_cast<const float4*>(bias)[i31];
        a0 += bv.x; a1 += bv.y; a2 += bv.z; a3 += bv.w;
    }
    if (valid) {
        if (BF16OUT) {
            uint2 o;
            o.x = cvt_pk_bf16(a0, a1);
            o.y = cvt_pk_bf16(a2, a3);
            reinterpret_cast<uint2*>(outp)[(size_t)gw * 32 + i31] = o;
        } else {
            float4 o = make_float4(a0, a1, a2, a3);
            reinterpret_cast<float4*>(outp)[(size_t)gw * 32 + i31] = o;
        }
    }
}

// ---------------- 8-wave fused GEMM: x = L2norm(A@W1+b1); tbl2 = dis*(x@W2) ----------------
// 512 threads. A-tile [64][128] bf16 staged into the FIRST 16KB of xt (sA/xt
// union: sA is dead after stage 1; the ssl barrier guarantees all stage-1 reads
// completed before xt writes overwrite it). LDS 34KB -> 4 blocks/CU. N split 8
// ways; W2 frags loaded after the norm barrier. bf16 packing via v_cvt_pk_bf16_f32.
// mfma_f32_16x16x32_bf16: A row=lane&15,k=(lane>>4)*8+j; C/D col=lane&15,row=(lane>>4)*4+r [m89].

__global__ __launch_bounds__(512, 4) void fused_gemm(const ushort* __restrict__ A,
                                                     const ushort* __restrict__ W1t,
                                                     const float* __restrict__ bias1,
                                                     const ushort* __restrict__ W2t,
                                                     const float* __restrict__ dsc,
                                                     ushort* __restrict__ out2, int M) {
    __shared__ __align__(16) ushort xt[64 * 256];   // 32KB; first 16KB doubles as sA
    __shared__ float ssl[8][64];
    int tid = threadIdx.x;
    int lane = tid & 63, wid = tid >> 6;   // 8 waves
    int g = lane >> 4, i15 = lane & 15;
    int koff = g * 8;
    int m0 = blockIdx.x * 64;

    // ---- stage A-tile into LDS (2 x 16B per thread, coalesced, swizzled dest) ----
    {
        const char* Ab = reinterpret_cast<const char*>(A);
        char* sAb = reinterpret_cast<char*>(xt);
#pragma unroll
        for (int j = 0; j < 2; ++j) {
            int byte = j * 8192 + tid * 16;
            int row = byte >> 8;
            int grow = m0 + row; if (grow >= M) grow = M - 1;
            bf16x8 v = *reinterpret_cast<const bf16x8*>(Ab + (size_t)grow * 256 + (byte & 255));
            *reinterpret_cast<bf16x8*>(sAb + (byte ^ ((row & 7) << 4))) = v;
        }
    }

    // preload W1 frags + bias for this wave's 32 stage-1 cols
    bf16x8 b1f[2][4];
    float bv[2];
#pragma unroll
    for (int ns = 0; ns < 2; ++ns) {
        int c = wid * 32 + ns * 16 + i15;
        const bf16x8* p = reinterpret_cast<const bf16x8*>(W1t + (size_t)c * 128 + koff);
#pragma unroll
        for (int ks = 0; ks < 4; ++ks) b1f[ns][ks] = p[ks * 4];
        bv[ns] = bias1[c];
    }
    __syncthreads();

    // ---- stage 1: gemm1 K=128 -> 32 cols/wave, A from LDS ----
    const char* sAb = reinterpret_cast<const char*>(xt);
    f32x4 acc[4][2];
#pragma unroll
    for (int ms = 0; ms < 4; ++ms)
#pragma unroll
        for (int ns = 0; ns < 2; ++ns) acc[ms][ns] = (f32x4){0.f, 0.f, 0.f, 0.f};
#pragma unroll
    for (int ks = 0; ks < 4; ++ks) {
        bf16x8 a[4];
#pragma unroll
        for (int ms = 0; ms < 4; ++ms) {
            int row = ms * 16 + i15;
            int byte = row * 256 + ks * 64 + g * 16;
            a[ms] = *reinterpret_cast<const bf16x8*>(sAb + (byte ^ ((row & 7) << 4)));
        }
#pragma unroll
        for (int ms = 0; ms < 4; ++ms)
#pragma unroll
            for (int ns = 0; ns < 2; ++ns)
                acc[ms][ns] = __builtin_amdgcn_mfma_f32_16x16x32_bf16(a[ms], b1f[ns][ks], acc[ms][ns], 0, 0, 0);
    }

    // bias + row sum-of-squares partials
    float ps[4][4];
#pragma unroll
    for (int ms = 0; ms < 4; ++ms)
#pragma unroll
        for (int r = 0; r < 4; ++r) {
            float s = 0.f;
#pragma unroll
            for (int ns = 0; ns < 2; ++ns) {
                float v = acc[ms][ns][r] + bv[ns];
                acc[ms][ns][r] = v;
                s += v * v;
            }
            ps[ms][r] = s;
        }
#pragma unroll
    for (int d = 1; d < 16; d <<= 1)
#pragma unroll
        for (int ms = 0; ms < 4; ++ms)
#pragma unroll
            for (int r = 0; r < 4; ++r) ps[ms][r] += __shfl_xor(ps[ms][r], d, 64);
    if (i15 == 0) {
#pragma unroll
        for (int ms = 0; ms < 4; ++ms)
#pragma unroll
            for (int r = 0; r < 4; ++r) ssl[wid][ms * 16 + g * 4 + r] = ps[ms][r];
    }
    __syncthreads();   // all stage-1 sA reads complete -> safe to overwrite (union)

    // normalize + write x-tile to LDS (swizzled, cvt_pk pairs of ns-cols)
#pragma unroll
    for (int ms = 0; ms < 4; ++ms)
#pragma unroll
        for (int r = 0; r < 4; ++r) {
            int rt = ms * 16 + g * 4 + r;
            float tot = 0.f;
#pragma unroll
            for (int w = 0; w < 8; ++w) tot += ssl[w][rt];
            float inv = 1.0f / fmaxf(sqrtf(tot), 1e-12f);
            int sw = (rt & 7) << 3;
            int c0 = wid * 32 + i15;
            uint pk = cvt_pk_bf16(acc[ms][0][r] * inv, acc[ms][1][r] * inv);
            xt[(rt * 256 + c0) ^ sw] = (ushort)pk;
            xt[(rt * 256 + c0 + 16) ^ sw] = (ushort)(pk >> 16);
        }
    __syncthreads();

    // W2 frags for this wave's 16 stage-2 cols
    bf16x8 b2f[8];
    {
        int c = wid * 16 + i15;
        const bf16x8* p = reinterpret_cast<const bf16x8*>(W2t + (size_t)c * 256 + koff);
#pragma unroll
        for (int ks = 0; ks < 8; ++ks) b2f[ks] = p[ks * 4];
    }

    // ---- stage 2: gemm2 K=256 -> 16 cols/wave, A from LDS ----
    f32x4 acc2[4];
#pragma unroll
    for (int ms = 0; ms < 4; ++ms) acc2[ms] = (f32x4){0.f, 0.f, 0.f, 0.f};
#pragma unroll
    for (int ks = 0; ks < 8; ++ks) {
        bf16x8 a2[4];
#pragma unroll
        for (int ms = 0; ms < 4; ++ms) {
            int rowA = ms * 16 + i15;
            int eb = (rowA * 256 + koff + ks * 32) ^ ((rowA & 7) << 3);
            a2[ms] = *reinterpret_cast<const bf16x8*>(&xt[eb]);
        }
#pragma unroll
        for (int ms = 0; ms < 4; ++ms)
            acc2[ms] = __builtin_amdgcn_mfma_f32_16x16x32_bf16(a2[ms], b2f[ks], acc2[ms], 0, 0, 0);
    }

    // epilogue: scale rows by dsc, cvt_pk row-pairs, write bf16 gather table
#pragma unroll
    for (int ms = 0; ms < 4; ++ms)
#pragma unroll
        for (int rp = 0; rp < 2; ++rp) {
            int r0 = rp * 2, r1 = rp * 2 + 1;
            int row0 = m0 + ms * 16 + g * 4 + r0;
            int row1 = row0 + 1;
            float s0 = dsc[row0 < M ? row0 : M - 1];
            float s1 = dsc[row1 < M ? row1 : M - 1];
            uint pk = cvt_pk_bf16(acc2[ms][r0] * s0, acc2[ms][r1] * s1);
            if (row0 < M) out2[(size_t)row0 * 128 + wid * 16 + i15] = (ushort)pk;
            if (row1 < M) out2[(size_t)row1 * 128 + wid * 16 + i15] = (ushort)(pk >> 16);
        }
}

// ---------------- launch ----------------

extern "C" void kernel_launch(void* const* d_in, const int* in_sizes, int n_in,
                              void* d_out, int out_size, void* d_ws, size_t ws_size,
                              hipStream_t stream) {
    const float* emb = (const float*)d_in[0];
    const float* W1 = (const float*)d_in[1];
    const float* b1 = (const float*)d_in[2];
    const float* W2 = (const float*)d_in[3];
    const float* b2 = (const float*)d_in[4];
    const int* eidx = (const int*)d_in[5];

    const int Nn = in_sizes[0] / 128;   // 100000
    const int E = in_sizes[5] / 2;      // 1600000
    const int* srcp = eidx;
    const int* dstp = eidx + E;

    float* ws = (float*)d_ws;
    size_t o = 0;
    uint* tbl1 = (uint*)(ws + o);  o += (size_t)(Nn + 1) * 64;   // dis*emb bf16 [Nn+1][128], row Nn = 0
    uint* axb = (uint*)(ws + o);   o += (size_t)Nn * 64;         // agg1 out bf16 [Nn][128]
    uint* tbl2 = (uint*)(ws + o);  o += (size_t)(Nn + 1) * 64;   // dis*h2 bf16 [Nn+1][128], row Nn = 0
    ushort* W1t = (ushort*)(ws + o); o += 128 * 256 / 2;   // [256][128]
    ushort* W2t = (ushort*)(ws + o); o += 256 * 128 / 2;   // [128][256]
    float* dis = ws + o;    o += Nn;
    int* gcur = (int*)(ws + o);   o += NBUCK + 1;
    int* offs = (int*)(ws + o);   o += Nn + 16;
    int* csr = (int*)(ws + o);    o += E;
    uint* pairs = (uint*)(ws + o); o += (size_t)NBUCK * BCAP;    // 12.8MB packed

    hipMemsetAsync(gcur, 0, (NBUCK + 1) * sizeof(int), stream);

    int B1B = 512;
    int chunk = (E + B1B - 1) / B1B;           // 3125
    bucket_kernel<<<769, 256, 0, stream>>>(srcp, dstp, gcur, pairs, E, chunk, W1, W1t, W2, W2t,
                                           tbl1 + (size_t)Nn * 64, tbl2 + (size_t)Nn * 64);
    csr_kernel<<<NBUCK, 256, 0, stream>>>(pairs, gcur, offs, dis, csr,
                                          (const float4*)emb, (ushort4*)tbl1, Nn, E);

    // layer 1: aggregate pre-scaled emb (bf16 out), then 8-wave fused GEMM -> tbl2
    agg2x<false, true><<<(Nn + 7) / 8, 256, 0, stream>>>((const uint2*)tbl1, offs, csr, dis, nullptr, axb, Nn);
    fused_gemm<<<(Nn + 63) / 64, 512, 0, stream>>>((const ushort*)axb, W1t, b1, W2t, dis, (ushort*)tbl2, Nn);

    // layer 2 aggregate + bias (fp32 out)
    agg2x<true, false><<<(Nn + 7) / 8, 256, 0, stream>>>((const uint2*)tbl2, offs, csr, dis, b2, d_out, Nn);
}